// Round 4
// baseline (230.220 us; speedup 1.0000x reference)
//
#include <hip/hip_runtime.h>
#include <math.h>

#define B 2
#define C 256
#define H 128
#define W 128
#define H2 256
#define W2 256

// ---------------- Kernel 1: channel mean ----------------
// One block per (b,h) row. 1024 threads = 32 channel-groups x 32 float4-columns.
__global__ __launch_bounds__(1024) void mean_kernel(const float* __restrict__ x,
                                                    float* __restrict__ mean) {
    int bh = blockIdx.x;            // 0 .. B*H-1
    int b = bh / H, h = bh % H;
    int tid = threadIdx.x;
    int g  = tid >> 5;              // channel group 0..31
    int w4 = tid & 31;              // float4 column 0..31

    const float4* xb = (const float4*)x + (size_t)b * C * (H * W / 4)
                       + (size_t)h * (W / 4) + w4;
    const size_t cstride = H * W / 4;

    float4 acc = make_float4(0.f, 0.f, 0.f, 0.f);
    #pragma unroll
    for (int i = 0; i < C / 32; ++i) {
        float4 v = xb[(size_t)(g * (C / 32) + i) * cstride];
        acc.x += v.x; acc.y += v.y; acc.z += v.z; acc.w += v.w;
    }

    __shared__ float4 sm[1024];
    sm[tid] = acc;
    __syncthreads();
    for (int s = 16; s >= 1; s >>= 1) {
        if (g < s) {
            float4 o = sm[tid + s * 32];
            acc.x += o.x; acc.y += o.y; acc.z += o.z; acc.w += o.w;
            sm[tid] = acc;
        }
        __syncthreads();
    }
    if (g == 0) {
        const float inv = 1.0f / C;
        float4 m = make_float4(acc.x * inv, acc.y * inv, acc.z * inv, acc.w * inv);
        ((float4*)mean)[(size_t)bh * (W / 4) + w4] = m;
    }
}

// ---------------- Kernel 2: fused weights + CARAFE apply ----------------
// Block = (b, 8x8 low-res tile). Phase 1: 256 threads compute softmax weights
// for the 16x16 up-pixel tile into LDS (mean tile + conv staged in LDS).
// Phase 2: 256 threads = 8 channel-slots x 8 rows x 4 col-pairs; each thread
// holds 18 float4 weights in regs and loops 32 channels (12 x-loads, 2 float4
// stores per channel).
__global__ __launch_bounds__(256) void fused_kernel(const float* __restrict__ x,
                                                    const float* __restrict__ mean,
                                                    const float* __restrict__ Woff,
                                                    const float* __restrict__ boff,
                                                    float* __restrict__ out) {
    __shared__ float sm[10][12];     // mean tile + zero halo
    __shared__ float sW[50];
    __shared__ float sb[2];
    __shared__ float sw[9][16][16];  // weights: [tap][up-row][up-col]

    int b  = blockIdx.z;
    int h0 = blockIdx.y * 8;
    int w0 = blockIdx.x * 8;
    int tid = threadIdx.x;

    // ---- stage mean tile (10x10 with zero halo) + conv weights ----
    if (tid < 100) {
        int lh = tid / 10, lw = tid % 10;
        int hh = h0 - 1 + lh, ww = w0 - 1 + lw;
        sm[lh][lw] = (hh >= 0 && hh < H && ww >= 0 && ww < W)
                         ? mean[(size_t)b * H * W + hh * W + ww] : 0.f;
    }
    if (tid >= 128 && tid < 178) sW[tid - 128] = Woff[tid - 128];
    if (tid >= 192 && tid < 194) sb[tid - 192] = boff[tid - 192];
    __syncthreads();

    // ---- phase 1: weights for up-pixel (ty,tx) in the 16x16 tile ----
    {
        int tx = tid & 15, ty = tid >> 4;

        float off0 = 0.f, off1 = 0.f;
        #pragma unroll
        for (int u = 0; u < 5; ++u) {
            int lh = ((ty + u - 2) >> 1) + 1;      // tile-relative, h0-independent
            #pragma unroll
            for (int v = 0; v < 5; ++v) {
                int lw = ((tx + v - 2) >> 1) + 1;
                float m = sm[lh][lw];
                off0 += m * sW[u * 5 + v];
                off1 += m * sW[25 + u * 5 + v];
            }
        }
        float s0 = tanhf(off0 + sb[0]) * 0.25f + ((tx & 1) ? 0.25f : -0.25f);
        float s1 = tanhf(off1 + sb[1]) * 0.25f + ((ty & 1) ? 0.25f : -0.25f);

        int lhc = (ty >> 1) + 1;
        int lwc = (tx >> 1) + 1;
        float mc = sm[lhc][lwc];

        float lg[9];
        float mx = -1e30f;
        #pragma unroll
        for (int k = 0; k < 9; ++k) {
            int di = k / 3 - 1, dj = k % 3 - 1;
            float pm = sm[lhc + di][lwc + dj];
            float g = pm - mc;
            float grad = 1.0f / (g * g + 1.0f);
            float d0 = s0 - (float)dj;
            float d1 = s1 - (float)di;
            float kern = 1.0f / (d0 * d0 + d1 * d1 + 0.2f);
            float l = grad * kern;
            lg[k] = l;
            mx = fmaxf(mx, l);
        }
        float sum = 0.f;
        #pragma unroll
        for (int k = 0; k < 9; ++k) { lg[k] = expf(lg[k] - mx); sum += lg[k]; }
        float inv = 1.0f / sum;
        #pragma unroll
        for (int k = 0; k < 9; ++k) sw[k][ty][tx] = lg[k] * inv;
    }
    __syncthreads();

    // ---- phase 2: apply across channels ----
    int cp = tid & 3;               // col-pair within tile (w = w0 + 2*cp..+1)
    int r  = (tid >> 2) & 7;        // low-res row within tile
    int s  = tid >> 5;              // channel slot 0..7

    int h = h0 + r;
    int w = w0 + 2 * cp;

    // 18 float4 weights from LDS (rows 2r,2r+1; cols 4cp..4cp+3)
    float4 wk[2][9];
    #pragma unroll
    for (int k = 0; k < 9; ++k) {
        wk[0][k] = *(const float4*)&sw[k][2 * r][4 * cp];
        wk[1][k] = *(const float4*)&sw[k][2 * r + 1][4 * cp];
    }

    // 3x4 x-patch footprint: rows h-1..h+1, cols w-1..w+2
    int off[3][4]; bool val[3][4];
    #pragma unroll
    for (int rr = 0; rr < 3; ++rr) {
        int hh = h - 1 + rr;
        #pragma unroll
        for (int cc = 0; cc < 4; ++cc) {
            int ww = w - 1 + cc;
            val[rr][cc] = (hh >= 0) & (hh < H) & (ww >= 0) & (ww < W);
            off[rr][cc] = hh * W + ww;
        }
    }

    const float* xb = x   + (size_t)(b * C + s * 32) * (H * W);
    float*       ob = out + (size_t)(b * C + s * 32) * (H2 * W2)
                          + (size_t)(2 * h) * W2 + 2 * w;

    #pragma unroll 2
    for (int cc = 0; cc < 32; ++cc) {
        float p[3][4];
        #pragma unroll
        for (int rr = 0; rr < 3; ++rr)
            #pragma unroll
            for (int c2 = 0; c2 < 4; ++c2)
                p[rr][c2] = val[rr][c2] ? xb[off[rr][c2]] : 0.f;

        #pragma unroll
        for (int pp = 0; pp < 2; ++pp) {
            float4 acc = make_float4(0.f, 0.f, 0.f, 0.f);
            #pragma unroll
            for (int k = 0; k < 9; ++k) {
                int ki = k / 3, kj = k % 3;
                float a  = p[ki][kj];       // pixel (h, w)   tap
                float bb = p[ki][kj + 1];   // pixel (h, w+1) tap
                acc.x += wk[pp][k].x * a;
                acc.y += wk[pp][k].y * a;
                acc.z += wk[pp][k].z * bb;
                acc.w += wk[pp][k].w * bb;
            }
            *(float4*)(ob + (size_t)pp * W2) = acc;
        }
        xb += H * W;
        ob += H2 * W2;
    }
}

extern "C" void kernel_launch(void* const* d_in, const int* in_sizes, int n_in,
                              void* d_out, int out_size, void* d_ws, size_t ws_size,
                              hipStream_t stream) {
    const float* x    = (const float*)d_in[0];
    const float* Woff = (const float*)d_in[1];
    const float* boff = (const float*)d_in[2];
    float* out = (float*)d_out;

    float* mean = (float*)d_ws;     // B*H*W floats (128 KiB)

    mean_kernel<<<B * H, 1024, 0, stream>>>(x, mean);

    dim3 grid(W / 8, H / 8, B);     // 16 x 16 x 2 = 512 blocks
    fused_kernel<<<grid, 256, 0, stream>>>(x, mean, Woff, boff, out);
}